// Round 6
// baseline (57.007 us; speedup 1.0000x reference)
//
#include <hip/hip_runtime.h>

#define TT 1024
#define NN 1024
#define TS (TT - 1)    // 1023 sss rows
#define BT 256         // 4 waves per block

typedef float v4f __attribute__((ext_vector_type(4)));

// Work unit = (sss row ts, 64-agent chunk). 1023*16 = 16368 units.
// One WAVE per unit, fully autonomous: no __syncthreads in the kernel.
__global__ __launch_bounds__(BT) void fused_traj_kernel(
    const float* __restrict__ a,
    const float* __restrict__ W1, const float* __restrict__ b1,
    const float* __restrict__ W2, const float* __restrict__ b2,
    const float* __restrict__ W3, const float* __restrict__ b3,
    const float* __restrict__ W4, const float* __restrict__ b4,
    const float* __restrict__ W5, const float* __restrict__ b5,
    const float* __restrict__ W6, const float* __restrict__ b6,
    float* __restrict__ out1, float* __restrict__ out64)
{
    __shared__ float sFeat[4][64 * 4];     // 1 KB per wave (4 KB total)

    const int tid  = threadIdx.x;
    const int wv   = tid >> 6;             // wave id in block, 0..3
    const int lane = tid & 63;

    const int u     = blockIdx.x * 4 + wv; // unit id, 0..16367
    const int ts    = u >> 4;              // sss row, 0..1022
    const int chunk = u & 15;              // agent chunk
    const int n     = chunk * 64 + lane;   // this lane's agent

    const float2* a2 = (const float2*)a;

    // ---- Phase 1: this lane's agent features ----
    const float2 p   = a2[(size_t)(ts + 1) * NN + n];
    const float2 pr  = a2[(size_t)ts * NN + n];
    const float2 pj  = a2[(size_t)(ts + 1) * NN + (NN - 1)];
    const float2 prj = a2[(size_t)ts * NN + (NN - 1)];

    const float dx  = p.x - pj.x, dy = p.y - pj.y;
    const float dis = sqrtf(dx * dx + dy * dy);

    const float ddx = p.x - pr.x, ddy = p.y - pr.y;
    const float v   = sqrtf(ddx * ddx + ddy * ddy) * 2.0f;   // / DT
    const float ang = atan2f(ddy, ddx);

    const float jdx = pj.x - prj.x, jdy = pj.y - prj.y;
    const float vj   = sqrtf(jdx * jdx + jdy * jdy) * 2.0f;
    const float angj = atan2f(jdy, jdx);

    const float mask = (dis <= 12.0f) ? 1.0f : 0.0f;

    const float x_m = W1[0] * p.x + W1[1] * (mask * pj.x) + b1[0];
    const float y_m = W2[0] * p.y + W2[1] * (mask * pj.y) + b2[0];
    const float v_m = W3[0] * v   + W3[1] * (mask * vj)   + b3[0];
    const float a_m = W4[0] * ang + W4[1] * (mask * angj) + b4[0];

    const float sss = W5[0] * x_m + W5[1] * y_m + W5[2] * v_m +
                      W5[3] * a_m + b5[0];

    __builtin_nontemporal_store(sss, &out1[(size_t)(ts + 1) * NN + n]);
    if (ts == 0)
        __builtin_nontemporal_store(sss, &out1[n]);   // duplicated row 0

    float* myFeat = sFeat[wv];
    myFeat[lane * 4 + 0] = x_m;
    myFeat[lane * 4 + 1] = y_m;
    myFeat[lane * 4 + 2] = v_m;
    myFeat[lane * 4 + 3] = a_m;

    // ---- W6 channel quad for this lane (fixed) ----
    const int c0 = (lane & 15) * 4;
    float4 w6r[4];
    float  b6r[4];
#pragma unroll
    for (int k = 0; k < 4; ++k) {
        w6r[k] = ((const float4*)W6)[c0 + k];
        b6r[k] = b6[c0 + k];
    }

    // Intra-wave LDS ordering only — no __syncthreads.
    __builtin_amdgcn_wave_barrier();

    // ---- Phase 2: this wave streams its 16 KB of out64 ----
    // float4 index g = lane + 64*it; agent_local = g>>4, chan quad = (g&15)*4
    float* dst  = out64 + ((size_t)(ts + 1) * NN + chunk * 64) * 64 + lane * 4;
    float* dst0 = out64 + ((size_t)chunk * 64) * 64 + lane * 4;

#pragma unroll
    for (int it = 0; it < 16; ++it) {
        const int al = (lane >> 4) + 4 * it;                 // agent_local
        const float4 ft = ((const float4*)myFeat)[al];       // 16-lane bcast

        v4f o;
        o.x = ft.x * w6r[0].x + ft.y * w6r[0].y + ft.z * w6r[0].z + ft.w * w6r[0].w + b6r[0];
        o.y = ft.x * w6r[1].x + ft.y * w6r[1].y + ft.z * w6r[1].z + ft.w * w6r[1].w + b6r[1];
        o.z = ft.x * w6r[2].x + ft.y * w6r[2].y + ft.z * w6r[2].z + ft.w * w6r[2].w + b6r[2];
        o.w = ft.x * w6r[3].x + ft.y * w6r[3].y + ft.z * w6r[3].z + ft.w * w6r[3].w + b6r[3];

        __builtin_nontemporal_store(o, (v4f*)(dst + it * 256));
        if (ts == 0)
            __builtin_nontemporal_store(o, (v4f*)(dst0 + it * 256));
    }
}

extern "C" void kernel_launch(void* const* d_in, const int* in_sizes, int n_in,
                              void* d_out, int out_size, void* d_ws, size_t ws_size,
                              hipStream_t stream)
{
    const float* a  = (const float*)d_in[0];
    const float* W1 = (const float*)d_in[1];
    const float* b1 = (const float*)d_in[2];
    const float* W2 = (const float*)d_in[3];
    const float* b2 = (const float*)d_in[4];
    const float* W3 = (const float*)d_in[5];
    const float* b3 = (const float*)d_in[6];
    const float* W4 = (const float*)d_in[7];
    const float* b4 = (const float*)d_in[8];
    const float* W5 = (const float*)d_in[9];
    const float* b5 = (const float*)d_in[10];
    const float* W6 = (const float*)d_in[11];
    const float* b6 = (const float*)d_in[12];

    float* out1  = (float*)d_out;                    // 1024*1024 floats
    float* out64 = out1 + (size_t)TT * NN;           // 1024*1024*64 floats

    const int grid = (TS * 16) / 4;                  // 16368 units / 4 waves = 4092
    fused_traj_kernel<<<grid, BT, 0, stream>>>(
        a, W1, b1, W2, b2, W3, b3, W4, b4, W5, b5, W6, b6, out1, out64);
}

// Round 7
// 48.227 us; speedup vs baseline: 1.1821x; 1.1821x over previous
//
#include <hip/hip_runtime.h>

#define TT 1024
#define NN 1024
#define TS (TT - 1)   // 1023 rows of actual computation
#define RPB 4         // t-rows per block

typedef float v4f __attribute__((ext_vector_type(4)));

__global__ __launch_bounds__(256) void fused_traj_kernel(
    const float* __restrict__ a,
    const float* __restrict__ W1, const float* __restrict__ b1,
    const float* __restrict__ W2, const float* __restrict__ b2,
    const float* __restrict__ W3, const float* __restrict__ b3,
    const float* __restrict__ W4, const float* __restrict__ b4,
    const float* __restrict__ W5, const float* __restrict__ b5,
    const float* __restrict__ W6, const float* __restrict__ b6,
    float* __restrict__ out1, float* __restrict__ out64)
{
    __shared__ float sFeat[RPB][64 * 4];   // feat[row][agent][4]

    const int bid    = blockIdx.x;
    const int tchunk = bid >> 4;           // 0..255
    const int n0     = (bid & 15) << 6;    // 0,64,...,960
    const int tid    = threadIdx.x;
    const int ts0    = tchunk * RPB;       // 0..1020
    const int rows   = min(RPB, TS - ts0); // 4 (3 for last chunk)

    // ---- Phase 1: all 256 threads — wave r computes row ts0+r ----
    const int r1   = tid >> 6;   // 0..3  (wave index = row)
    const int lane = tid & 63;

    if (r1 < rows) {
        const int ts = ts0 + r1;
        const int n  = n0 + lane;
        const float2* a2 = (const float2*)a;
        const float2 p   = a2[(size_t)(ts + 1) * NN + n];
        const float2 pr  = a2[(size_t)ts * NN + n];
        const float2 pj  = a2[(size_t)(ts + 1) * NN + (NN - 1)];
        const float2 prj = a2[(size_t)ts * NN + (NN - 1)];

        const float dx  = p.x - pj.x, dy = p.y - pj.y;
        const float dis = sqrtf(dx * dx + dy * dy);

        const float ddx = p.x - pr.x, ddy = p.y - pr.y;
        const float v   = sqrtf(ddx * ddx + ddy * ddy) * 2.0f;  // / DT
        const float ang = atan2f(ddy, ddx);

        const float jdx = pj.x - prj.x, jdy = pj.y - prj.y;
        const float vj   = sqrtf(jdx * jdx + jdy * jdy) * 2.0f;
        const float angj = atan2f(jdy, jdx);

        const float mask = (dis <= 12.0f) ? 1.0f : 0.0f;

        const float x_m = W1[0] * p.x + W1[1] * (mask * pj.x) + b1[0];
        const float y_m = W2[0] * p.y + W2[1] * (mask * pj.y) + b2[0];
        const float v_m = W3[0] * v   + W3[1] * (mask * vj)   + b3[0];
        const float a_m = W4[0] * ang + W4[1] * (mask * angj) + b4[0];

        const float sss = W5[0] * x_m + W5[1] * y_m + W5[2] * v_m +
                          W5[3] * a_m + b5[0];

        out1[(size_t)(ts + 1) * NN + n] = sss;
        if (ts == 0) out1[n] = sss;     // duplicated first row

        sFeat[r1][lane * 4 + 0] = x_m;
        sFeat[r1][lane * 4 + 1] = y_m;
        sFeat[r1][lane * 4 + 2] = v_m;
        sFeat[r1][lane * 4 + 3] = a_m;
    }

    // ---- This thread's 4 fixed W6 channels in registers ----
    const int c0 = (tid * 4) & 63;
    float4 w6r[4];
    float  b6r[4];
#pragma unroll
    for (int k = 0; k < 4; ++k) {
        w6r[k] = ((const float4*)W6)[c0 + k];   // row (c0+k) of W6 (64x4)
        b6r[k] = b6[c0 + k];
    }

    __syncthreads();

    // ---- Phase 2: coalesced out64 writes, 4 rows per block ----
    for (int r = 0; r < rows; ++r) {
        const int ts = ts0 + r;
        float* dst = out64 + ((size_t)(ts + 1) * NN + n0) * 64;

#pragma unroll
        for (int j = 0; j < 4; ++j) {
            const int pair = (tid >> 4) + 16 * j;
            const float4 ft = ((const float4*)sFeat[r])[pair]; // 16-lane bcast

            v4f o;
            o.x = ft.x * w6r[0].x + ft.y * w6r[0].y + ft.z * w6r[0].z + ft.w * w6r[0].w + b6r[0];
            o.y = ft.x * w6r[1].x + ft.y * w6r[1].y + ft.z * w6r[1].z + ft.w * w6r[1].w + b6r[1];
            o.z = ft.x * w6r[2].x + ft.y * w6r[2].y + ft.z * w6r[2].z + ft.w * w6r[2].w + b6r[2];
            o.w = ft.x * w6r[3].x + ft.y * w6r[3].y + ft.z * w6r[3].z + ft.w * w6r[3].w + b6r[3];

            const int f = pair * 64 + c0;        // float4-aligned
            *(v4f*)(dst + f) = o;
            if (ts == 0)
                *(v4f*)(out64 + (size_t)n0 * 64 + f) = o;
        }
    }
}

extern "C" void kernel_launch(void* const* d_in, const int* in_sizes, int n_in,
                              void* d_out, int out_size, void* d_ws, size_t ws_size,
                              hipStream_t stream)
{
    const float* a  = (const float*)d_in[0];
    const float* W1 = (const float*)d_in[1];
    const float* b1 = (const float*)d_in[2];
    const float* W2 = (const float*)d_in[3];
    const float* b2 = (const float*)d_in[4];
    const float* W3 = (const float*)d_in[5];
    const float* b3 = (const float*)d_in[6];
    const float* W4 = (const float*)d_in[7];
    const float* b4 = (const float*)d_in[8];
    const float* W5 = (const float*)d_in[9];
    const float* b5 = (const float*)d_in[10];
    const float* W6 = (const float*)d_in[11];
    const float* b6 = (const float*)d_in[12];

    float* out1  = (float*)d_out;                    // 1024*1024 floats
    float* out64 = out1 + (size_t)TT * NN;           // 1024*1024*64 floats

    const int grid = ((TS + RPB - 1) / RPB) * (NN / 64);   // 256 * 16 = 4096
    fused_traj_kernel<<<grid, 256, 0, stream>>>(
        a, W1, b1, W2, b2, W3, b3, W4, b4, W5, b5, W6, b6, out1, out64);
}